// Round 1
// baseline (294.230 us; speedup 1.0000x reference)
//
#include <hip/hip_runtime.h>
#include <math.h>

// Problem constants (reference: B=64, T=8192, X=32, fp32)
constexpr int B_  = 64;
constexpr int T_  = 8192;
constexpr int X_  = 32;
constexpr int CH  = 256;          // chunks per (b,x) row
constexpr int TC  = T_ / CH;      // 32 timesteps per chunk
constexpr int XG  = X_ / 4;       // 8 float4 groups per timestep
constexpr float NEG_LARGE = -1.0e6f;

// Recurrence: out = min(phi, max(psi, carry))  ==  clamp(carry; l=min(phi,psi), h=phi)
// Clamp monoid: composed chunk == (L,H) = (f(-inf), f(+inf)); apply = min(H, max(L, c)).
// All ops are exact float selections -> bit-exact vs sequential reference.

__device__ __forceinline__ void compose_pair(const float4 p, const float4 q,
                                             float4& L, float4& H) {
    float l;
    l = fminf(p.x, q.x); L.x = fminf(p.x, fmaxf(l, L.x)); H.x = fminf(p.x, fmaxf(l, H.x));
    l = fminf(p.y, q.y); L.y = fminf(p.y, fmaxf(l, L.y)); H.y = fminf(p.y, fmaxf(l, H.y));
    l = fminf(p.z, q.z); L.z = fminf(p.z, fmaxf(l, L.z)); H.z = fminf(p.z, fmaxf(l, H.z));
    l = fminf(p.w, q.w); L.w = fminf(p.w, fmaxf(l, L.w)); H.w = fminf(p.w, fmaxf(l, H.w));
}

__device__ __forceinline__ void apply_step(const float4 p, const float4 q, float4& c) {
    c.x = fminf(p.x, fmaxf(q.x, c.x));
    c.y = fminf(p.y, fmaxf(q.y, c.y));
    c.z = fminf(p.z, fmaxf(q.z, c.z));
    c.w = fminf(p.w, fmaxf(q.w, c.w));
}

// ---------------- Pass 1: per-chunk clamp reduction ----------------
// grid: B_*CH*XG / 256 blocks of 256. One thread = one (b, chunk, x4-group).
__global__ __launch_bounds__(256) void until_pass1(
        const float4* __restrict__ phi, const float4* __restrict__ psi,
        float4* __restrict__ Lw, float4* __restrict__ Hw) {
    const int tid = blockIdx.x * 256 + threadIdx.x;
    const int xg  = tid & (XG - 1);
    const int bj  = tid / XG;             // b*CH + j
    const int j   = bj & (CH - 1);
    const int b   = bj / CH;
    const size_t base = ((size_t)b * T_ + (size_t)j * TC) * XG + xg;

    float4 L = make_float4(-INFINITY, -INFINITY, -INFINITY, -INFINITY);
    float4 H = make_float4( INFINITY,  INFINITY,  INFINITY,  INFINITY);
    #pragma unroll 4
    for (int t = 0; t < TC; ++t) {
        const float4 p = phi[base + (size_t)t * XG];
        const float4 q = psi[base + (size_t)t * XG];
        compose_pair(p, q, L, H);
    }
    Lw[(size_t)bj * XG + xg] = L;
    Hw[(size_t)bj * XG + xg] = H;
}

// ---------------- Pass 2: scan chunk clamps -> per-chunk carry-in ----------------
// B_*XG = 512 threads total; each serially scans CH=256 chunk summaries for its row group.
__global__ __launch_bounds__(256) void until_pass2(
        const float4* __restrict__ Lw, const float4* __restrict__ Hw,
        float4* __restrict__ Cw) {
    const int tid = blockIdx.x * 256 + threadIdx.x;   // [0, B_*XG)
    const int xg  = tid & (XG - 1);
    const int b   = tid / XG;
    float4 c = make_float4(NEG_LARGE, NEG_LARGE, NEG_LARGE, NEG_LARGE);
    #pragma unroll 8
    for (int j = 0; j < CH; ++j) {
        const size_t idx = ((size_t)b * CH + j) * XG + xg;
        Cw[idx] = c;                      // carry-IN for chunk j
        const float4 L = Lw[idx];
        const float4 H = Hw[idx];
        c.x = fminf(H.x, fmaxf(L.x, c.x));
        c.y = fminf(H.y, fmaxf(L.y, c.y));
        c.z = fminf(H.z, fmaxf(L.z, c.z));
        c.w = fminf(H.w, fmaxf(L.w, c.w));
    }
}

// ---------------- Pass 3: apply — exact sequential recurrence per chunk ----------------
__global__ __launch_bounds__(256) void until_pass3(
        const float4* __restrict__ phi, const float4* __restrict__ psi,
        const float4* __restrict__ Cw, float4* __restrict__ out) {
    const int tid = blockIdx.x * 256 + threadIdx.x;
    const int xg  = tid & (XG - 1);
    const int bj  = tid / XG;
    const int j   = bj & (CH - 1);
    const int b   = bj / CH;
    const size_t base = ((size_t)b * T_ + (size_t)j * TC) * XG + xg;

    float4 c = Cw[(size_t)bj * XG + xg];
    #pragma unroll 4
    for (int t = 0; t < TC; ++t) {
        const float4 p = phi[base + (size_t)t * XG];
        const float4 q = psi[base + (size_t)t * XG];
        apply_step(p, q, c);
        out[base + (size_t)t * XG] = c;
    }
}

extern "C" void kernel_launch(void* const* d_in, const int* in_sizes, int n_in,
                              void* d_out, int out_size, void* d_ws, size_t ws_size,
                              hipStream_t stream) {
    const float4* phi = (const float4*)d_in[0];   // trace1
    const float4* psi = (const float4*)d_in[1];   // trace2
    float4* out = (float4*)d_out;

    const size_t nsum = (size_t)B_ * CH * XG;     // 131072 float4 per array
    float4* Lw = (float4*)d_ws;
    float4* Hw = Lw + nsum;
    float4* Cw = Hw + nsum;

    const int threads_main = B_ * CH * XG;        // 131072
    until_pass1<<<threads_main / 256, 256, 0, stream>>>(phi, psi, Lw, Hw);
    until_pass2<<<(B_ * XG) / 256, 256, 0, stream>>>(Lw, Hw, Cw);
    until_pass3<<<threads_main / 256, 256, 0, stream>>>(phi, psi, Cw, out);
}

// Round 4
// 208.325 us; speedup vs baseline: 1.4124x; 1.4124x over previous
//
#include <hip/hip_runtime.h>
#include <math.h>

// Problem constants (reference: B=64, T=8192, X=32, fp32)
constexpr int B_  = 64;
constexpr int T_  = 8192;
constexpr int X_  = 32;
constexpr int CH  = 256;          // chunks per (b,x) row
constexpr int TC  = T_ / CH;      // 32 timesteps per chunk
constexpr int XG  = X_ / 4;       // 8 float4 groups per timestep
constexpr int CPL = CH / 64;      // chunks per lane in pass2 wave-scan = 4
constexpr float NEG_LARGE = -1.0e6f;

typedef float vf4 __attribute__((ext_vector_type(4)));  // native vector for nontemporal builtin

// Recurrence: out = min(phi, max(psi, carry))  ==  clamp(carry; l=min(phi,psi), h=phi)
// Clamp monoid: chunk == (L,H) = (f(-inf), f(+inf)); apply = min(H, max(L, c)).
// Composition (g after f): L' = clamp_g(L_f), H' = clamp_g(H_f) — associative,
// all ops exact float selections -> bit-exact vs sequential reference.

__device__ __forceinline__ float4 clamp4(const float4 L, const float4 H, const float4 c) {
    return make_float4(fminf(H.x, fmaxf(L.x, c.x)),
                       fminf(H.y, fmaxf(L.y, c.y)),
                       fminf(H.z, fmaxf(L.z, c.z)),
                       fminf(H.w, fmaxf(L.w, c.w)));
}

__device__ __forceinline__ void compose_pair(const float4 p, const float4 q,
                                             float4& L, float4& H) {
    float l;
    l = fminf(p.x, q.x); L.x = fminf(p.x, fmaxf(l, L.x)); H.x = fminf(p.x, fmaxf(l, H.x));
    l = fminf(p.y, q.y); L.y = fminf(p.y, fmaxf(l, L.y)); H.y = fminf(p.y, fmaxf(l, H.y));
    l = fminf(p.z, q.z); L.z = fminf(p.z, fmaxf(l, L.z)); H.z = fminf(p.z, fmaxf(l, H.z));
    l = fminf(p.w, q.w); L.w = fminf(p.w, fmaxf(l, L.w)); H.w = fminf(p.w, fmaxf(l, H.w));
}

__device__ __forceinline__ void apply_step(const float4 p, const float4 q, float4& c) {
    c.x = fminf(p.x, fmaxf(q.x, c.x));
    c.y = fminf(p.y, fmaxf(q.y, c.y));
    c.z = fminf(p.z, fmaxf(q.z, c.z));
    c.w = fminf(p.w, fmaxf(q.w, c.w));
}

__device__ __forceinline__ float4 shfl_up4(const float4 v, int d) {
    return make_float4(__shfl_up(v.x, d, 64), __shfl_up(v.y, d, 64),
                       __shfl_up(v.z, d, 64), __shfl_up(v.w, d, 64));
}

// ---------------- Pass 1: per-chunk clamp reduction ----------------
__global__ __launch_bounds__(256) void until_pass1(
        const float4* __restrict__ phi, const float4* __restrict__ psi,
        float4* __restrict__ Lw, float4* __restrict__ Hw) {
    const int tid = blockIdx.x * 256 + threadIdx.x;
    const int xg  = tid & (XG - 1);
    const int bj  = tid / XG;             // b*CH + j
    const int j   = bj & (CH - 1);
    const int b   = bj / CH;
    const size_t base = ((size_t)b * T_ + (size_t)j * TC) * XG + xg;

    float4 L = make_float4(-INFINITY, -INFINITY, -INFINITY, -INFINITY);
    float4 H = make_float4( INFINITY,  INFINITY,  INFINITY,  INFINITY);
    #pragma unroll 4
    for (int t = 0; t < TC; ++t) {
        const float4 p = phi[base + (size_t)t * XG];
        const float4 q = psi[base + (size_t)t * XG];
        compose_pair(p, q, L, H);
    }
    Lw[(size_t)bj * XG + xg] = L;
    Hw[(size_t)bj * XG + xg] = H;
}

// ---------------- Pass 2: wave-parallel scan of chunk clamps ----------------
// One wave per (b, xg) row: 512 waves. Each lane composes CPL=4 chunks serially,
// 6-step shfl_up inclusive scan across 64 lanes, then emits per-chunk carry-ins.
__global__ __launch_bounds__(256) void until_pass2(
        const float4* __restrict__ Lw, const float4* __restrict__ Hw,
        float4* __restrict__ Cw) {
    const int tid  = blockIdx.x * 256 + threadIdx.x;
    const int lane = tid & 63;
    const int w    = tid >> 6;            // wave id = row id, [0, B_*XG)
    const int xg   = w & (XG - 1);
    const int b    = w / XG;

    // Load + serially compose this lane's 4 chunks (keep summaries for re-apply).
    float4 cL[CPL], cH[CPL];
    float4 L = make_float4(-INFINITY, -INFINITY, -INFINITY, -INFINITY);
    float4 H = make_float4( INFINITY,  INFINITY,  INFINITY,  INFINITY);
    #pragma unroll
    for (int k = 0; k < CPL; ++k) {
        const int j = lane * CPL + k;
        const size_t idx = ((size_t)b * CH + j) * XG + xg;
        cL[k] = Lw[idx];
        cH[k] = Hw[idx];
        L = clamp4(cL[k], cH[k], L);      // compose: clamp_k applied to both bounds
        H = clamp4(cL[k], cH[k], H);
    }

    // Inclusive Hillis-Steele scan across lanes (clamp composition).
    #pragma unroll
    for (int d = 1; d < 64; d <<= 1) {
        const float4 Lp = shfl_up4(L, d);
        const float4 Hp = shfl_up4(H, d);
        if (lane >= d) {
            const float4 nL = clamp4(L, H, Lp);   // self ∘ prev
            const float4 nH = clamp4(L, H, Hp);
            L = nL; H = nH;
        }
    }

    // Exclusive prefix -> carry-in at this lane's first chunk.
    const float4 Lex = shfl_up4(L, 1);
    const float4 Hex = shfl_up4(H, 1);
    const float4 c0 = make_float4(NEG_LARGE, NEG_LARGE, NEG_LARGE, NEG_LARGE);
    float4 c = (lane == 0) ? c0 : clamp4(Lex, Hex, c0);

    #pragma unroll
    for (int k = 0; k < CPL; ++k) {
        const int j = lane * CPL + k;
        const size_t idx = ((size_t)b * CH + j) * XG + xg;
        Cw[idx] = c;                      // carry-IN for chunk j
        c = clamp4(cL[k], cH[k], c);
    }
}

// ---------------- Pass 3: apply — exact sequential recurrence per chunk ----------------
__global__ __launch_bounds__(256) void until_pass3(
        const float4* __restrict__ phi, const float4* __restrict__ psi,
        const float4* __restrict__ Cw, float4* __restrict__ out) {
    const int tid = blockIdx.x * 256 + threadIdx.x;
    const int xg  = tid & (XG - 1);
    const int bj  = tid / XG;
    const int j   = bj & (CH - 1);
    const int b   = bj / CH;
    const size_t base = ((size_t)b * T_ + (size_t)j * TC) * XG + xg;

    float4 c = Cw[(size_t)bj * XG + xg];
    #pragma unroll 4
    for (int t = 0; t < TC; ++t) {
        const float4 p = phi[base + (size_t)t * XG];
        const float4 q = psi[base + (size_t)t * XG];
        apply_step(p, q, c);
        // Nontemporal store: don't let the 64 MiB output evict L3-warm phi/psi.
        vf4 cv; cv.x = c.x; cv.y = c.y; cv.z = c.z; cv.w = c.w;
        __builtin_nontemporal_store(cv, reinterpret_cast<vf4*>(&out[base + (size_t)t * XG]));
    }
}

extern "C" void kernel_launch(void* const* d_in, const int* in_sizes, int n_in,
                              void* d_out, int out_size, void* d_ws, size_t ws_size,
                              hipStream_t stream) {
    const float4* phi = (const float4*)d_in[0];   // trace1
    const float4* psi = (const float4*)d_in[1];   // trace2
    float4* out = (float4*)d_out;

    const size_t nsum = (size_t)B_ * CH * XG;     // 131072 float4 per array
    float4* Lw = (float4*)d_ws;
    float4* Hw = Lw + nsum;
    float4* Cw = Hw + nsum;

    const int threads_main = B_ * CH * XG;        // 131072
    until_pass1<<<threads_main / 256, 256, 0, stream>>>(phi, psi, Lw, Hw);
    until_pass2<<<(B_ * XG * 64) / 256, 256, 0, stream>>>(Lw, Hw, Cw);
    until_pass3<<<threads_main / 256, 256, 0, stream>>>(phi, psi, Cw, out);
}

// Round 7
// 199.312 us; speedup vs baseline: 1.4762x; 1.0452x over previous
//
#include <hip/hip_runtime.h>
#include <math.h>

// Problem constants (reference: B=64, T=8192, X=32, fp32)
constexpr int B_  = 64;
constexpr int T_  = 8192;
constexpr int X_  = 32;
constexpr int XG  = X_ / 4;       // 8 float4 groups per timestep
constexpr float NEG_LARGE = -1.0e6f;

typedef float vf4 __attribute__((ext_vector_type(4)));  // native vector for nontemporal builtin

// Recurrence: out = min(phi, max(psi, carry))  ==  clamp(carry; l=min(phi,psi), h=phi)
// Clamp monoid: chunk == (L,H) = (f(-inf), f(+inf)); apply = min(H, max(L, c)).
// Composition (g after f): L' = clamp_g(L_f), H' = clamp_g(H_f) — associative,
// all ops exact float selections -> bit-exact vs sequential reference.

__device__ __forceinline__ float4 clamp4(const float4 L, const float4 H, const float4 c) {
    return make_float4(fminf(H.x, fmaxf(L.x, c.x)),
                       fminf(H.y, fmaxf(L.y, c.y)),
                       fminf(H.z, fmaxf(L.z, c.z)),
                       fminf(H.w, fmaxf(L.w, c.w)));
}

__device__ __forceinline__ void compose_pair(const float4 p, const float4 q,
                                             float4& L, float4& H) {
    float l;
    l = fminf(p.x, q.x); L.x = fminf(p.x, fmaxf(l, L.x)); H.x = fminf(p.x, fmaxf(l, H.x));
    l = fminf(p.y, q.y); L.y = fminf(p.y, fmaxf(l, L.y)); H.y = fminf(p.y, fmaxf(l, H.y));
    l = fminf(p.z, q.z); L.z = fminf(p.z, fmaxf(l, L.z)); H.z = fminf(p.z, fmaxf(l, H.z));
    l = fminf(p.w, q.w); L.w = fminf(p.w, fmaxf(l, L.w)); H.w = fminf(p.w, fmaxf(l, H.w));
}

__device__ __forceinline__ void apply_step(const float4 p, const float4 q, float4& c) {
    c.x = fminf(p.x, fmaxf(q.x, c.x));
    c.y = fminf(p.y, fmaxf(q.y, c.y));
    c.z = fminf(p.z, fmaxf(q.z, c.z));
    c.w = fminf(p.w, fmaxf(q.w, c.w));
}

__device__ __forceinline__ float4 shfl_up4(const float4 v, int d) {
    return make_float4(__shfl_up(v.x, d, 64), __shfl_up(v.y, d, 64),
                       __shfl_up(v.z, d, 64), __shfl_up(v.w, d, 64));
}

// ---------------- Pass 1: per-chunk clamp reduction ----------------
// Batched loads (8 timesteps = 16 float4 in flight) for deep MLP; grid = B_*CH*XG/256.
template<int CH>
__global__ __launch_bounds__(256) void until_pass1(
        const float4* __restrict__ phi, const float4* __restrict__ psi,
        float4* __restrict__ Lw, float4* __restrict__ Hw) {
    constexpr int TC = T_ / CH;
    const int tid = blockIdx.x * 256 + threadIdx.x;
    const int xg  = tid & (XG - 1);
    const int bj  = tid / XG;             // b*CH + j
    const int j   = bj & (CH - 1);
    const int b   = bj / CH;
    const size_t base = ((size_t)b * T_ + (size_t)j * TC) * XG + xg;

    float4 L = make_float4(-INFINITY, -INFINITY, -INFINITY, -INFINITY);
    float4 H = make_float4( INFINITY,  INFINITY,  INFINITY,  INFINITY);
    constexpr int BATCH = 8;
    for (int t0 = 0; t0 < TC; t0 += BATCH) {
        float4 p[BATCH], q[BATCH];
        #pragma unroll
        for (int k = 0; k < BATCH; ++k) p[k] = phi[base + (size_t)(t0 + k) * XG];
        #pragma unroll
        for (int k = 0; k < BATCH; ++k) q[k] = psi[base + (size_t)(t0 + k) * XG];
        #pragma unroll
        for (int k = 0; k < BATCH; ++k) compose_pair(p[k], q[k], L, H);
    }
    Lw[(size_t)bj * XG + xg] = L;
    Hw[(size_t)bj * XG + xg] = H;
}

// ---------------- Pass 2: wave-parallel scan of chunk clamps ----------------
// One wave per (b, xg) row. Lane composes CPL chunks (reload-based, no reg arrays),
// 6-step shfl_up composition scan, then writes carry-ins IN PLACE over Lw.
template<int CH>
__global__ __launch_bounds__(256) void until_pass2(
        float4* __restrict__ Lw, const float4* __restrict__ Hw) {
    constexpr int CPL = CH / 64;
    const int tid  = blockIdx.x * 256 + threadIdx.x;
    const int lane = tid & 63;
    const int w    = tid >> 6;            // wave id = row id, [0, B_*XG)
    const int xg   = w & (XG - 1);
    const int b    = w / XG;
    const size_t rowbase = (size_t)b * CH * XG + xg;

    // Compose this lane's CPL chunks (ascending j).
    float4 L = make_float4(-INFINITY, -INFINITY, -INFINITY, -INFINITY);
    float4 H = make_float4( INFINITY,  INFINITY,  INFINITY,  INFINITY);
    #pragma unroll
    for (int k = 0; k < CPL; ++k) {
        const size_t idx = rowbase + (size_t)(lane * CPL + k) * XG;
        const float4 lL = Lw[idx];
        const float4 lH = Hw[idx];
        L = clamp4(lL, lH, L);
        H = clamp4(lL, lH, H);
    }

    // Inclusive Hillis-Steele scan across lanes (clamp composition).
    #pragma unroll
    for (int d = 1; d < 64; d <<= 1) {
        const float4 Lp = shfl_up4(L, d);
        const float4 Hp = shfl_up4(H, d);
        if (lane >= d) {
            const float4 nL = clamp4(L, H, Lp);   // self ∘ prev
            const float4 nH = clamp4(L, H, Hp);
            L = nL; H = nH;
        }
    }

    // Exclusive prefix -> carry-in at this lane's first chunk.
    const float4 Lex = shfl_up4(L, 1);
    const float4 Hex = shfl_up4(H, 1);
    const float4 c0 = make_float4(NEG_LARGE, NEG_LARGE, NEG_LARGE, NEG_LARGE);
    float4 c = (lane == 0) ? c0 : clamp4(Lex, Hex, c0);

    // Walk forward, reloading summaries (L2-hot) and overwriting Lw with carry-ins.
    #pragma unroll
    for (int k = 0; k < CPL; ++k) {
        const size_t idx = rowbase + (size_t)(lane * CPL + k) * XG;
        const float4 lL = Lw[idx];
        const float4 lH = Hw[idx];
        Lw[idx] = c;                      // carry-IN for this chunk
        c = clamp4(lL, lH, c);
    }
}

// ---------------- Pass 3: apply — exact sequential recurrence per chunk ----------------
template<int CH>
__global__ __launch_bounds__(256) void until_pass3(
        const float4* __restrict__ phi, const float4* __restrict__ psi,
        const float4* __restrict__ Cw, float4* __restrict__ out) {
    constexpr int TC = T_ / CH;
    const int tid = blockIdx.x * 256 + threadIdx.x;
    const int xg  = tid & (XG - 1);
    const int bj  = tid / XG;
    const int j   = bj & (CH - 1);
    const int b   = bj / CH;
    const size_t base = ((size_t)b * T_ + (size_t)j * TC) * XG + xg;

    float4 c = Cw[(size_t)bj * XG + xg];
    constexpr int BATCH = 8;
    for (int t0 = 0; t0 < TC; t0 += BATCH) {
        float4 p[BATCH], q[BATCH];
        #pragma unroll
        for (int k = 0; k < BATCH; ++k) p[k] = phi[base + (size_t)(t0 + k) * XG];
        #pragma unroll
        for (int k = 0; k < BATCH; ++k) q[k] = psi[base + (size_t)(t0 + k) * XG];
        #pragma unroll
        for (int k = 0; k < BATCH; ++k) {
            apply_step(p[k], q[k], c);
            // Nontemporal store: don't let the 64 MiB output evict L3-warm phi/psi.
            vf4 cv; cv.x = c.x; cv.y = c.y; cv.z = c.z; cv.w = c.w;
            __builtin_nontemporal_store(cv,
                reinterpret_cast<vf4*>(&out[base + (size_t)(t0 + k) * XG]));
        }
    }
}

template<int CH>
static void launch_all(const float4* phi, const float4* psi, float4* out,
                       void* d_ws, hipStream_t stream) {
    const size_t nsum = (size_t)B_ * CH * XG;
    float4* Lw = (float4*)d_ws;           // becomes carry-in array after pass2
    float4* Hw = Lw + nsum;
    const int threads_main = B_ * CH * XG;
    until_pass1<CH><<<threads_main / 256, 256, 0, stream>>>(phi, psi, Lw, Hw);
    until_pass2<CH><<<(B_ * XG * 64) / 256, 256, 0, stream>>>(Lw, Hw);
    until_pass3<CH><<<threads_main / 256, 256, 0, stream>>>(phi, psi, Lw, out);
}

extern "C" void kernel_launch(void* const* d_in, const int* in_sizes, int n_in,
                              void* d_out, int out_size, void* d_ws, size_t ws_size,
                              hipStream_t stream) {
    const float4* phi = (const float4*)d_in[0];   // trace1
    const float4* psi = (const float4*)d_in[1];   // trace2
    float4* out = (float4*)d_out;

    // CH=512 needs 2 * 64*512*8 * 16 B = 8 MiB of workspace; fall back if short.
    const size_t need512 = 2ull * B_ * 512 * XG * sizeof(float4);
    if (ws_size >= need512) {
        launch_all<512>(phi, psi, out, d_ws, stream);
    } else {
        launch_all<256>(phi, psi, out, d_ws, stream);
    }
}